// Round 4
// baseline (292.550 us; speedup 1.0000x reference)
//
#include <hip/hip_runtime.h>
#include <stdint.h>

#define Tdim 128
#define Zdim 100
#define Sdim 6
#define Hdim 64
#define ZB   3200           // Z*B
#define F1   512
#define F2   128
#define Mrows (ZB * Tdim)   // 409600

typedef _Float16 f16x8 __attribute__((ext_vector_type(8)));
typedef _Float16 f16x4 __attribute__((ext_vector_type(4)));
typedef float f32x4 __attribute__((ext_vector_type(4)));
typedef float f32x2 __attribute__((ext_vector_type(2)));
typedef uint32_t u32x4 __attribute__((ext_vector_type(4)));

__device__ __forceinline__ float fast_rcp(float x) {
  return __builtin_amdgcn_rcpf(x);   // v_rcp_f32: 1 trans op, no div-fixup chain
}

// ---------------------------------------------------------------- prep
// Wf[192][96] fp16: [W_hh | W_ih | 0] per gate (K=96 fused), for the GRU.
// w1p frag-linear: [kt][ntl][kfrag][lane][8].  32768 f16.
// w2p frag-linear: [kt][nt][lane][8].          65536 f16.
__global__ __launch_bounds__(256) void prep_kernel(
    const float* __restrict__ W_ih, const float* __restrict__ W_hh,
    const float* __restrict__ w1, const float* __restrict__ w2,
    _Float16* __restrict__ Wf, _Float16* __restrict__ w1p,
    _Float16* __restrict__ w2p) {
  int i = blockIdx.x * 256 + threadIdx.x;     // grid covers 116736
  if (i < 192 * 96) {
    int g = i / 96, k = i - g * 96;
    float v = (k < 64) ? W_hh[g * 64 + k] : ((k < 70) ? W_ih[g * 6 + (k - 64)] : 0.f);
    Wf[i] = (_Float16)v;
  }
  int j = i - 192 * 96;
  if (j >= 0 && j < 32768) {
    int kt = j >> 11, ntl = (j >> 10) & 1, kf = (j >> 9) & 1;
    int lane = (j >> 3) & 63, e = j & 7;
    int q = lane >> 4, c = lane & 15;
    int row = kt * 32 + ntl * 16 + c;
    int h = kf * 32 + q * 8 + e;
    w1p[j] = (_Float16)w1[row * 64 + h];
  }
  int l = j - 32768;
  if (l >= 0 && l < 65536) {
    int kt = l >> 12, nt = (l >> 9) & 7;
    int lane = (l >> 3) & 63, e = l & 7;
    int q = lane >> 4, c = lane & 15;
    int row = nt * 16 + c;
    int k = kt * 32 + q * 8 + e;
    w2p[l] = (_Float16)w2[row * 512 + k];
  }
}

// ---------------------------------------------------------------- GRU v3: barrier-free
// ONE wave owns 16 sequences end-to-end: all 12 gate-tiles (3 gates x 4
// n-subtiles, K=96 fused [W_hh|W_ih|0]) = 36 MFMA/step in a single wave.
// h never crosses waves -> hist LDS is wave-private -> ZERO barriers in the
// 128-step loop (ordering via compiler lgkmcnt only). 200 single-wave blocks
// spread ~1/SIMD; VGPR-fat (~300) is intentional: 1 wave/SIMD is the target.
// x is NOT preloaded to LDS: 6 floats/row/step prefetched from global (L2-
// resident, 1 step ahead). sx dumped in 16-step chunks for coalescing.
__global__ __launch_bounds__(64, 1) void gru_kernel(
    const float* __restrict__ x, const _Float16* __restrict__ Wf,
    const float* __restrict__ b_ih, const float* __restrict__ b_hh,
    _Float16* __restrict__ sx) {
  __shared__ __align__(16) _Float16 hist[16][16][72];  // 36,864 B, wave-private
  const int lane = threadIdx.x & 63;
  const int c = lane & 15;                    // MFMA col = sequence row
  const int q = lane >> 4;                    // quad
  const int wid = blockIdx.x;                 // 0..199 -> rows wid*16..+15

  // per-lane x pointer for row c (row nr = z*32 + b; x layout (b,t,z,s))
  const int nr = wid * 16 + c;
  const float* px = x + (size_t)(nr & 31) * (Tdim * Zdim * Sdim)
                      + (size_t)(nr >> 5) * Sdim;

  // ---- A-frags: [gate][nt][kf], A[m=c][k=q*8+j], K=96 fused  (144 VGPR)
  f16x8 A[3][4][3];
#pragma unroll
  for (int g = 0; g < 3; g++)
#pragma unroll
    for (int nt = 0; nt < 4; nt++)
#pragma unroll
      for (int kf = 0; kf < 3; kf++)
        A[g][nt][kf] = *(const f16x8*)(Wf + (size_t)(g * 64 + nt * 16 + c) * 96
                                       + kf * 32 + q * 8);

  // ---- biases in D-layout (m = nt*16 + q*4 + r)
  f32x4 Crz[2][4], Cnh[4], Cni[4];
#pragma unroll
  for (int g = 0; g < 2; g++)
#pragma unroll
    for (int nt = 0; nt < 4; nt++) {
      f32x4 bi = *(const f32x4*)(b_ih + g * 64 + nt * 16 + q * 4);
      f32x4 bh = *(const f32x4*)(b_hh + g * 64 + nt * 16 + q * 4);
#pragma unroll
      for (int r = 0; r < 4; r++) Crz[g][nt][r] = bi[r] + bh[r];
    }
#pragma unroll
  for (int nt = 0; nt < 4; nt++) {
    Cnh[nt] = *(const f32x4*)(b_hh + 128 + nt * 16 + q * 4);
    Cni[nt] = *(const f32x4*)(b_ih + 128 + nt * 16 + q * 4);
  }

  const uint32_t xmask = (q == 0) ? 0xffffffffu : 0u;

  f16x8 Bh0 = {0, 0, 0, 0, 0, 0, 0, 0};
  f16x8 Bh1 = {0, 0, 0, 0, 0, 0, 0, 0};
  f32x4 hprev[4] = {{0.f, 0.f, 0.f, 0.f}, {0.f, 0.f, 0.f, 0.f},
                    {0.f, 0.f, 0.f, 0.f}, {0.f, 0.f, 0.f, 0.f}};

  // ---- x(0) -> Bx -> seeds for t=0 (x-projection + bias as MFMA C)
  f32x4 Sr[4], Sz[4], Sni[4];
  f32x2 xa, xb, xc;
  xa = *(const f32x2*)(px + 0);
  xb = *(const f32x2*)(px + 2);
  xc = *(const f32x2*)(px + 4);
  f16x8 Bx;
  {
    Bx[0] = (_Float16)xa[0]; Bx[1] = (_Float16)xa[1];
    Bx[2] = (_Float16)xb[0]; Bx[3] = (_Float16)xb[1];
    Bx[4] = (_Float16)xc[0]; Bx[5] = (_Float16)xc[1];
    Bx[6] = (_Float16)0.f;   Bx[7] = (_Float16)0.f;
    u32x4 xv = *(u32x4*)&Bx;
    xv[0] &= xmask; xv[1] &= xmask; xv[2] &= xmask; xv[3] &= xmask;
    Bx = *(f16x8*)&xv;
  }
#pragma unroll
  for (int nt = 0; nt < 4; nt++) {
    Sr[nt]  = __builtin_amdgcn_mfma_f32_16x16x32_f16(A[0][nt][2], Bx, Crz[0][nt], 0, 0, 0);
    Sz[nt]  = __builtin_amdgcn_mfma_f32_16x16x32_f16(A[1][nt][2], Bx, Crz[1][nt], 0, 0, 0);
    Sni[nt] = __builtin_amdgcn_mfma_f32_16x16x32_f16(A[2][nt][2], Bx, Cni[nt], 0, 0, 0);
  }

#pragma unroll 1
  for (int t = 0; t < Tdim; t++) {
    // ---- prefetch x(t+1) early (latency hidden under this step's work)
    const int tn = (t + 1 < Tdim) ? t + 1 : Tdim - 1;
    const float* pn = px + (size_t)tn * (Zdim * Sdim);
    xa = *(const f32x2*)(pn + 0);
    xb = *(const f32x2*)(pn + 2);
    xc = *(const f32x2*)(pn + 4);

    // ---- h-dependent MFMAs: 24, two dep stages, seeded with x-projection
    f32x4 Dr[4], Dz[4], Dnh[4];
#pragma unroll
    for (int nt = 0; nt < 4; nt++)
      Dnh[nt] = __builtin_amdgcn_mfma_f32_16x16x32_f16(A[2][nt][0], Bh0, Cnh[nt], 0, 0, 0);
#pragma unroll
    for (int nt = 0; nt < 4; nt++)
      Dr[nt] = __builtin_amdgcn_mfma_f32_16x16x32_f16(A[0][nt][0], Bh0, Sr[nt], 0, 0, 0);
#pragma unroll
    for (int nt = 0; nt < 4; nt++)
      Dz[nt] = __builtin_amdgcn_mfma_f32_16x16x32_f16(A[1][nt][0], Bh0, Sz[nt], 0, 0, 0);
#pragma unroll
    for (int nt = 0; nt < 4; nt++)
      Dnh[nt] = __builtin_amdgcn_mfma_f32_16x16x32_f16(A[2][nt][1], Bh1, Dnh[nt], 0, 0, 0);
#pragma unroll
    for (int nt = 0; nt < 4; nt++)
      Dr[nt] = __builtin_amdgcn_mfma_f32_16x16x32_f16(A[0][nt][1], Bh1, Dr[nt], 0, 0, 0);
#pragma unroll
    for (int nt = 0; nt < 4; nt++)
      Dz[nt] = __builtin_amdgcn_mfma_f32_16x16x32_f16(A[1][nt][1], Bh1, Dz[nt], 0, 0, 0);

    // ---- activation (identical math to v2) + wave-private hist write
    const int tc = t & 15;
#pragma unroll
    for (int nt = 0; nt < 4; nt++) {
      f16x4 pk;
#pragma unroll
      for (int r = 0; r < 4; r++) {
        float er = __expf(-Dr[nt][r]);
        float rr = fast_rcp(1.f + er);
        float ez = __expf(-Dz[nt][r]);
        float zg = fast_rcp(1.f + ez);
        float na = Sni[nt][r] + rr * Dnh[nt][r];
        float en = __expf(2.f * na);
        float nn = 1.f - 2.f * fast_rcp(en + 1.f);
        float hnew = nn + zg * (hprev[nt][r] - nn);
        hprev[nt][r] = hnew;
        pk[r] = (_Float16)hnew;
      }
      *(f16x4*)&hist[tc][c][nt * 16 + q * 4] = pk;
    }

    // ---- Bx(t+1) + x-projection seeds for t+1 (fills MFMA pipe during act)
    {
      Bx[0] = (_Float16)xa[0]; Bx[1] = (_Float16)xa[1];
      Bx[2] = (_Float16)xb[0]; Bx[3] = (_Float16)xb[1];
      Bx[4] = (_Float16)xc[0]; Bx[5] = (_Float16)xc[1];
      Bx[6] = (_Float16)0.f;   Bx[7] = (_Float16)0.f;
      u32x4 xv = *(u32x4*)&Bx;
      xv[0] &= xmask; xv[1] &= xmask; xv[2] &= xmask; xv[3] &= xmask;
      Bx = *(f16x8*)&xv;
    }
#pragma unroll
    for (int nt = 0; nt < 4; nt++) {
      Sr[nt]  = __builtin_amdgcn_mfma_f32_16x16x32_f16(A[0][nt][2], Bx, Crz[0][nt], 0, 0, 0);
      Sz[nt]  = __builtin_amdgcn_mfma_f32_16x16x32_f16(A[1][nt][2], Bx, Crz[1][nt], 0, 0, 0);
      Sni[nt] = __builtin_amdgcn_mfma_f32_16x16x32_f16(A[2][nt][2], Bx, Cni[nt], 0, 0, 0);
    }

    // ---- h back as B-frags (wave-private: lgkmcnt only, NO barrier)
    Bh0 = *(const f16x8*)&hist[tc][c][q * 8];
    Bh1 = *(const f16x8*)&hist[tc][c][32 + q * 8];

    // ---- coalesced 16-step chunk dump (single wave, no sync needed)
    if (tc == 15) {
      const int t0 = t - 15;
#pragma unroll 1
      for (int row = 0; row < 16; ++row) {
        _Float16* dst = sx + ((size_t)(wid * 16 + row) * Tdim + t0) * Hdim;
#pragma unroll
        for (int it = 0; it < 2; ++it) {
          int idx = it * 64 + lane;           // 0..127
          int tcc = idx >> 3, hd8 = idx & 7;
          f16x8 vv = *(const f16x8*)&hist[tcc][row][hd8 * 8];
          *(f16x8*)(dst + (size_t)tcc * 64 + hd8 * 8) = vv;
        }
      }
    }
  }
}

// ---------------------------------------------------------------- fused MLP
// (standalone R1 version, proven 92 us: w1 fully LDS-staged once, w2 frags
// direct from global/L2, rep transpose software-pipelined across kt)
__global__ __launch_bounds__(256, 2) void mlp_kernel(
    const _Float16* __restrict__ sx, const _Float16* __restrict__ w1p,
    const _Float16* __restrict__ w2p, const float* __restrict__ b1,
    const float* __restrict__ b2, const float* __restrict__ w3,
    const float* __restrict__ b3, float* __restrict__ out) {
  __shared__ __align__(16) _Float16 w1s[32768];        // 64 KB: all w1 frags
  __shared__ __align__(16) _Float16 rep[4][4][512];    // 16 KB [wave][g][...]
  const int tid = threadIdx.x;
  const int lane = tid & 63;
  const int wave = tid >> 6;
  const int c = lane & 15;
  const int q = lane >> 4;
  const size_t m0 = ((size_t)blockIdx.x * 4 + wave) * 64;

  // ---- stage all of w1 into LDS (one time; 64 KB/block from L2/L3)
  {
    const u32x4* src = (const u32x4*)w1p;   // 4096 u32x4
    u32x4* dst = (u32x4*)w1s;
#pragma unroll
    for (int i = 0; i < 16; i++)
      dst[i * 256 + tid] = src[i * 256 + tid];
  }

  // ---- resident activations (rows) as B-frags for the whole kernel
  f16x8 Bs[4][2];
#pragma unroll
  for (int g = 0; g < 4; g++)
#pragma unroll
    for (int kk = 0; kk < 2; kk++)
      Bs[g][kk] = *(const f16x8*)(sx + (m0 + g * 16 + c) * Hdim + kk * 32 + q * 8);

  f32x4 acc2[4][8];
#pragma unroll
  for (int g = 0; g < 4; g++)
#pragma unroll
    for (int nt = 0; nt < 8; nt++) acc2[g][nt] = (f32x4){0.f, 0.f, 0.f, 0.f};

  __syncthreads();                            // w1s ready (only barrier)

  // ---- prologue: layer1 for kt=0 into rep
  {
#pragma unroll
    for (int ntl = 0; ntl < 2; ntl++) {
      f16x8 A0 = *(const f16x8*)&w1s[ntl * 1024 + lane * 8];
      f16x8 A1 = *(const f16x8*)&w1s[ntl * 1024 + 512 + lane * 8];
      f32x4 bb = *(const f32x4*)(b1 + ntl * 16 + q * 4);
      const int roff = ((2 * ntl + (q >> 1)) * 16 + c) * 8 + (q & 1) * 4;
#pragma unroll
      for (int g = 0; g < 4; g++) {
        f32x4 cc = __builtin_amdgcn_mfma_f32_16x16x32_f16(A0, Bs[g][0], bb, 0, 0, 0);
        cc = __builtin_amdgcn_mfma_f32_16x16x32_f16(A1, Bs[g][1], cc, 0, 0, 0);
        f16x4 pk;
#pragma unroll
        for (int r = 0; r < 4; r++)
          pk[r] = (_Float16)(cc[r] > 0.f ? cc[r] : 0.f);
        *(f16x4*)&rep[wave][g][roff] = pk;
      }
    }
  }

#pragma unroll 1
  for (int kt = 0; kt < 16; kt++) {
    const int ktn = kt + 1;
    const bool more = (ktn < 16);
    // ---- issue ALL loads up front (latency hidden under MFMAs below)
    f16x8 A2[8];                              // layer2 weights for kt (global)
#pragma unroll
    for (int nt = 0; nt < 8; nt++)
      A2[nt] = *(const f16x8*)(w2p + (size_t)kt * 4096 + nt * 512 + lane * 8);
    f16x8 W0[2], W1[2];                       // layer1 weights for kt+1 (LDS)
    f32x4 bb[2];
    {
      const int kts = more ? ktn : kt;        // harmless re-read on last iter
#pragma unroll
      for (int ntl = 0; ntl < 2; ntl++) {
        W0[ntl] = *(const f16x8*)&w1s[kts * 2048 + ntl * 1024 + lane * 8];
        W1[ntl] = *(const f16x8*)&w1s[kts * 2048 + ntl * 1024 + 512 + lane * 8];
        bb[ntl] = *(const f32x4*)(b1 + kts * 32 + ntl * 16 + q * 4);
      }
    }
    f16x8 Ba[4];                              // a1(kt), written last iteration
#pragma unroll
    for (int g = 0; g < 4; g++)
      Ba[g] = *(const f16x8*)&rep[wave][g][lane * 8];

    // ---- layer1 for kt+1 -> rep (WAR on Ba covered by the read->write gap)
    if (more) {
#pragma unroll
      for (int ntl = 0; ntl < 2; ntl++) {
        const int roff = ((2 * ntl + (q >> 1)) * 16 + c) * 8 + (q & 1) * 4;
#pragma unroll
        for (int g = 0; g < 4; g++) {
          f32x4 cc = __builtin_amdgcn_mfma_f32_16x16x32_f16(W0[ntl], Bs[g][0], bb[ntl], 0, 0, 0);
          cc = __builtin_amdgcn_mfma_f32_16x16x32_f16(W1[ntl], Bs[g][1], cc, 0, 0, 0);
          f16x4 pk;
#pragma unroll
          for (int r = 0; r < 4; r++)
            pk[r] = (_Float16)(cc[r] > 0.f ? cc[r] : 0.f);
          *(f16x4*)&rep[wave][g][roff] = pk;
        }
      }
    }

    // ---- layer2 partial for kt
#pragma unroll
    for (int nt = 0; nt < 8; nt++)
#pragma unroll
      for (int g = 0; g < 4; g++)
        acc2[g][nt] = __builtin_amdgcn_mfma_f32_16x16x32_f16(A2[nt], Ba[g], acc2[g][nt], 0, 0, 0);
  }

  // ---- layer3: out[row] = sum relu(a2 + b2) * w3 + b3
  float part[4] = {0.f, 0.f, 0.f, 0.f};
#pragma unroll
  for (int nt = 0; nt < 8; nt++) {
    f32x4 bb = *(const f32x4*)(b2 + nt * 16 + q * 4);
    f32x4 ww = *(const f32x4*)(w3 + nt * 16 + q * 4);
#pragma unroll
    for (int g = 0; g < 4; g++) {
#pragma unroll
      for (int r = 0; r < 4; r++) {
        float v = acc2[g][nt][r] + bb[r];
        v = v > 0.f ? v : 0.f;
        part[g] = fmaf(v, ww[r], part[g]);
      }
    }
  }
#pragma unroll
  for (int g = 0; g < 4; g++) {
    part[g] += __shfl_xor(part[g], 16, 64);
    part[g] += __shfl_xor(part[g], 32, 64);
  }
  // lane (c,q) writes row q*16+c of this wave's 64 rows
  float pv = (q == 0) ? part[0] : (q == 1) ? part[1] : (q == 2) ? part[2] : part[3];
  out[m0 + q * 16 + c] = pv + b3[0];
}

// ----------------------------------------------------------------
extern "C" void kernel_launch(void* const* d_in, const int* in_sizes, int n_in,
                              void* d_out, int out_size, void* d_ws, size_t ws_size,
                              hipStream_t stream) {
  const float* x    = (const float*)d_in[0];
  const float* W_ih = (const float*)d_in[1];
  const float* W_hh = (const float*)d_in[2];
  const float* b_ih = (const float*)d_in[3];
  const float* b_hh = (const float*)d_in[4];
  const float* w1   = (const float*)d_in[5];
  const float* b1   = (const float*)d_in[6];
  const float* w2   = (const float*)d_in[7];
  const float* b2   = (const float*)d_in[8];
  const float* w3   = (const float*)d_in[9];
  const float* b3   = (const float*)d_in[10];
  float* out = (float*)d_out;

  char* ws = (char*)d_ws;
  _Float16* sxf = (_Float16*)ws;                          // 52,428,800 B
  _Float16* Wf  = (_Float16*)(ws + 52428800);             // 36,864 B
  _Float16* w1p = (_Float16*)(ws + 52428800 + 36864);     // 65,536 B
  _Float16* w2p = (_Float16*)(ws + 52428800 + 36864 + 65536); // 131,072 B

  hipLaunchKernelGGL(prep_kernel, dim3(456), dim3(256), 0, stream,
                     W_ih, W_hh, w1, w2, Wf, w1p, w2p);
  hipLaunchKernelGGL(gru_kernel, dim3(ZB / 16), dim3(64), 0, stream,
                     x, Wf, b_ih, b_hh, sxf);
  hipLaunchKernelGGL(mlp_kernel, dim3(Mrows / 256), dim3(256), 0, stream,
                     sxf, w1p, w2p, b1, b2, w3, b3, out);
}

// Round 5
// 290.433 us; speedup vs baseline: 1.0073x; 1.0073x over previous
//
#include <hip/hip_runtime.h>
#include <stdint.h>

#define Tdim 128
#define Zdim 100
#define Sdim 6
#define Hdim 64
#define ZB   3200           // Z*B
#define F1   512
#define F2   128
#define Mrows (ZB * Tdim)   // 409600
#define NGRU 200            // gru-role blocks (ZB/16), one 16-seq stream each
#define NMLP 1600           // mlp-role blocks (NGRU * 8 chunks)

typedef _Float16 f16x8 __attribute__((ext_vector_type(8)));
typedef _Float16 f16x4 __attribute__((ext_vector_type(4)));
typedef float f32x4 __attribute__((ext_vector_type(4)));
typedef uint32_t u32x4 __attribute__((ext_vector_type(4)));

__device__ __forceinline__ float fast_rcp(float x) {
  return __builtin_amdgcn_rcpf(x);   // v_rcp_f32: 1 trans op, no div-fixup chain
}

// ---------------------------------------------------------------- prep
// Wf[192][96] fp16: [W_hh | W_ih | 0] per gate (K=96 fused), for the GRU.
// w1p frag-linear: [kt][ntl][kfrag][lane][8].  32768 f16.
// w2p frag-linear: [kt][nt][lane][8].          65536 f16.
// Also zeroes the producer-consumer sync area (1600 flags + 1 ticket).
__global__ __launch_bounds__(256) void prep_kernel(
    const float* __restrict__ W_ih, const float* __restrict__ W_hh,
    const float* __restrict__ w1, const float* __restrict__ w2,
    _Float16* __restrict__ Wf, _Float16* __restrict__ w1p,
    _Float16* __restrict__ w2p, unsigned int* __restrict__ sync) {
  int i = blockIdx.x * 256 + threadIdx.x;     // grid covers 116736
  if (i < NMLP + 1) sync[i] = 0u;             // flags[1600] + ticket
  if (i < 192 * 96) {
    int g = i / 96, k = i - g * 96;
    float v = (k < 64) ? W_hh[g * 64 + k] : ((k < 70) ? W_ih[g * 6 + (k - 64)] : 0.f);
    Wf[i] = (_Float16)v;
  }
  int j = i - 192 * 96;
  if (j >= 0 && j < 32768) {
    int kt = j >> 11, ntl = (j >> 10) & 1, kf = (j >> 9) & 1;
    int lane = (j >> 3) & 63, e = j & 7;
    int q = lane >> 4, c = lane & 15;
    int row = kt * 32 + ntl * 16 + c;
    int h = kf * 32 + q * 8 + e;
    w1p[j] = (_Float16)w1[row * 64 + h];
  }
  int l = j - 32768;
  if (l >= 0 && l < 65536) {
    int kt = l >> 12, nt = (l >> 9) & 7;
    int lane = (l >> 3) & 63, e = l & 7;
    int q = lane >> 4, c = lane & 15;
    int row = nt * 16 + c;
    int k = kt * 32 + q * 8 + e;
    w2p[l] = (_Float16)w2[row * 512 + k];
  }
}

// ---------------------------------------------------------------- fused GRU+MLP v2
// 1800 blocks x 256 threads, LDS union = 81,920 B exactly -> 2 blocks/CU.
// Role by atomic ticket: first NGRU started blocks take GRU (resident by
// definition -> deadlock-free). GRU role = proven 4-wave gate-split step,
// ONE 16-seq stream per block (per-block barrier -> independent streams
// desync; co-resident MLP blocks soak the GRU's idle issue slots).
// MLP role = proven 256-thr mlp block consuming one (gru-block, chunk) item
// of 16 seqs x 16 timesteps = 256 rows (fine granularity, 1600 consumers).
__global__ __launch_bounds__(256, 2) void fused_kernel(
    const float* __restrict__ x, const _Float16* __restrict__ Wf,
    const float* __restrict__ b_ih, const float* __restrict__ b_hh,
    _Float16* __restrict__ sx, const _Float16* __restrict__ w1p,
    const _Float16* __restrict__ w2p, const float* __restrict__ b1,
    const float* __restrict__ b2, const float* __restrict__ w3,
    const float* __restrict__ b3, float* __restrict__ out,
    unsigned int* __restrict__ flags, unsigned int* __restrict__ ticket) {
  union SmemU {
    struct { _Float16 hist[16][16][72]; _Float16 xs[Tdim][16][8]; } g;  // 69,632 B
    struct { _Float16 w1s[32768]; _Float16 rep[4][4][512]; } m;         // 81,920 B
  };
  __shared__ __align__(16) SmemU smem;
  __shared__ int s_tk;
  const int tid = threadIdx.x;
  if (tid == 0) s_tk = (int)atomicAdd(ticket, 1u);
  __syncthreads();
  const int tk = s_tk;

  const int lane = tid & 63;
  const int w = tid >> 6;                     // wave id 0..3
  const int c = lane & 15;                    // MFMA col
  const int q = lane >> 4;                    // quad

  if (tk < NGRU) {
    // =============================== GRU role ===========================
    const int gb = tk;                        // seqs gb*16 .. gb*16+15
    auto& hist = smem.g.hist;
    auto& xs = smem.g.xs;

    // ---- preload x for this block's 16 rows, pre-converted to fp16
    for (int i = 0; i < 8; i++) {
      int idx = i * 256 + tid;                // 0..2047 = (t, row)
      int t = idx >> 4, row = idx & 15;
      int nr = gb * 16 + row;                 // n = z*32 + b
      const float* p = x + (size_t)(nr & 31) * (Tdim * Zdim * Sdim)
                         + (size_t)t * (Zdim * Sdim) + (size_t)(nr >> 5) * Sdim;
      f16x8 v;
      v[0] = (_Float16)p[0]; v[1] = (_Float16)p[1]; v[2] = (_Float16)p[2];
      v[3] = (_Float16)p[3]; v[4] = (_Float16)p[4]; v[5] = (_Float16)p[5];
      v[6] = (_Float16)0.f;  v[7] = (_Float16)0.f;
      *(f16x8*)&xs[t][row][0] = v;
    }

    const int gr0 = w * 16;                   // r-gate tile base
    const int gz0 = 64 + w * 16;              // z-gate tile base
    const int gn0 = 128 + w * 16;             // n-gate tile base

    // A-frags: A[m=c][k=q*8+j] per 16-gate tile, K=96 fused [h|x|0]
    f16x8 Ar[3], Az[3], Anh[2], Ani;
#pragma unroll
    for (int kf = 0; kf < 3; kf++) {
      Ar[kf] = *(const f16x8*)(Wf + (size_t)(gr0 + c) * 96 + kf * 32 + q * 8);
      Az[kf] = *(const f16x8*)(Wf + (size_t)(gz0 + c) * 96 + kf * 32 + q * 8);
    }
    Anh[0] = *(const f16x8*)(Wf + (size_t)(gn0 + c) * 96 + q * 8);
    Anh[1] = *(const f16x8*)(Wf + (size_t)(gn0 + c) * 96 + 32 + q * 8);
    Ani    = *(const f16x8*)(Wf + (size_t)(gn0 + c) * 96 + 64 + q * 8);

    // biases in D-layout (gate-local m = q*4 + r)
    f32x4 Cr, Cz, Cnh, Cni;
    {
      f32x4 bir = *(const f32x4*)(b_ih + gr0 + q * 4);
      f32x4 bhr = *(const f32x4*)(b_hh + gr0 + q * 4);
      f32x4 biz = *(const f32x4*)(b_ih + gz0 + q * 4);
      f32x4 bhz = *(const f32x4*)(b_hh + gz0 + q * 4);
#pragma unroll
      for (int r = 0; r < 4; r++) { Cr[r] = bir[r] + bhr[r]; Cz[r] = biz[r] + bhz[r]; }
      Cnh = *(const f32x4*)(b_hh + gn0 + q * 4);
      Cni = *(const f32x4*)(b_ih + gn0 + q * 4);
    }

    const uint32_t xmask = (q == 0) ? 0xffffffffu : 0u;

    __syncthreads();                          // xs ready

    f16x8 Bh0 = {0, 0, 0, 0, 0, 0, 0, 0};
    f16x8 Bh1 = {0, 0, 0, 0, 0, 0, 0, 0};
    f32x4 hprev = {0.f, 0.f, 0.f, 0.f};

    f32x4 Dr_s, Dz_s, Dni_s;
    {
      u32x4 xv = *(const u32x4*)&xs[0][c][0];
      xv[0] &= xmask; xv[1] &= xmask; xv[2] &= xmask; xv[3] &= xmask;
      f16x8 Bx = *(f16x8*)&xv;
      Dni_s = __builtin_amdgcn_mfma_f32_16x16x32_f16(Ani, Bx, Cni, 0, 0, 0);
      Dr_s  = __builtin_amdgcn_mfma_f32_16x16x32_f16(Ar[2], Bx, Cr, 0, 0, 0);
      Dz_s  = __builtin_amdgcn_mfma_f32_16x16x32_f16(Az[2], Bx, Cz, 0, 0, 0);
    }

#pragma unroll 1
    for (int tch = 0; tch < 8; tch++) {
#pragma unroll 1
      for (int tc = 0; tc < 16; tc++) {
        const int t = tch * 16 + tc;
        f32x4 Dnh = __builtin_amdgcn_mfma_f32_16x16x32_f16(Anh[0], Bh0, Cnh, 0, 0, 0);
        f32x4 Dr  = __builtin_amdgcn_mfma_f32_16x16x32_f16(Ar[0], Bh0, Dr_s, 0, 0, 0);
        f32x4 Dz  = __builtin_amdgcn_mfma_f32_16x16x32_f16(Az[0], Bh0, Dz_s, 0, 0, 0);
        Dnh = __builtin_amdgcn_mfma_f32_16x16x32_f16(Anh[1], Bh1, Dnh, 0, 0, 0);
        Dr  = __builtin_amdgcn_mfma_f32_16x16x32_f16(Ar[1], Bh1, Dr, 0, 0, 0);
        Dz  = __builtin_amdgcn_mfma_f32_16x16x32_f16(Az[1], Bh1, Dz, 0, 0, 0);

        f16x4 pk;
#pragma unroll
        for (int r = 0; r < 4; r++) {
          float er = __expf(-Dr[r]);
          float rr = fast_rcp(1.f + er);
          float ez = __expf(-Dz[r]);
          float zg = fast_rcp(1.f + ez);
          float na = Dni_s[r] + rr * Dnh[r];
          float en = __expf(2.f * na);
          float nn = 1.f - 2.f * fast_rcp(en + 1.f);
          float hnew = nn + zg * (hprev[r] - nn);
          hprev[r] = hnew;
          pk[r] = (_Float16)hnew;
        }
        *(f16x4*)&hist[tc][c][w * 16 + q * 4] = pk;

        if (t + 1 < Tdim) {
          u32x4 xv = *(const u32x4*)&xs[t + 1][c][0];
          xv[0] &= xmask; xv[1] &= xmask; xv[2] &= xmask; xv[3] &= xmask;
          f16x8 Bx = *(f16x8*)&xv;
          Dni_s = __builtin_amdgcn_mfma_f32_16x16x32_f16(Ani, Bx, Cni, 0, 0, 0);
          Dr_s  = __builtin_amdgcn_mfma_f32_16x16x32_f16(Ar[2], Bx, Cr, 0, 0, 0);
          Dz_s  = __builtin_amdgcn_mfma_f32_16x16x32_f16(Az[2], Bx, Cz, 0, 0, 0);
        }
        __syncthreads();                      // h exchange across the 4 gate waves
        Bh0 = *(const f16x8*)&hist[tc][c][q * 8];
        Bh1 = *(const f16x8*)&hist[tc][c][32 + q * 8];
      }
      // coalesced dump of the 16-step chunk; wave w handles rows 4w..4w+3
      {
        const int t0 = tch * 16;
#pragma unroll
        for (int rr2 = 0; rr2 < 4; rr2++) {
          const int row = w * 4 + rr2;
          const int nrow = gb * 16 + row;
          _Float16* dst = sx + (size_t)nrow * Tdim * Hdim + (size_t)t0 * Hdim;
#pragma unroll
          for (int it = 0; it < 2; it++) {
            int idx = it * 64 + lane;         // 0..127
            int tcc = idx >> 3, hd8 = idx & 7;
            f16x8 vv = *(const f16x8*)&hist[tcc][row][hd8 * 8];
            *(f16x8*)(dst + tcc * 64 + hd8 * 8) = vv;
          }
        }
        __syncthreads();                      // dump drained (vmcnt 0) + hist reusable
        if (tid == 0) {
          __threadfence();                    // agent-scope release of sx
          atomicAdd(&flags[gb * 8 + tch], 1u);// publish chunk
        }
      }
    }
  } else {
    // =============================== MLP role ===========================
    const int mid = tk - NGRU;                // 0..1599
    const int ch  = mid / NGRU;               // chunk 0..7 (early tickets -> early chunks)
    const int gbm = mid % NGRU;               // producer gru block
    auto& w1s = smem.m.w1s;
    auto& rep = smem.m.rep;

    // ---- stage all of w1 into LDS while waiting (64 KB, L2-resident)
    {
      const u32x4* srcw = (const u32x4*)w1p;  // 4096 u32x4
      u32x4* dstw = (u32x4*)w1s;
#pragma unroll
      for (int i = 0; i < 16; i++)
        dstw[i * 256 + tid] = srcw[i * 256 + tid];
    }
    // ---- wait for producer chunk
    if (tid == 0) {
      while (__hip_atomic_load(&flags[gbm * 8 + ch], __ATOMIC_RELAXED,
                               __HIP_MEMORY_SCOPE_AGENT) == 0u)
        __builtin_amdgcn_s_sleep(2);
      (void)__hip_atomic_load(&flags[gbm * 8 + ch], __ATOMIC_ACQUIRE,
                              __HIP_MEMORY_SCOPE_AGENT);  // invalidate caches
    }
    __syncthreads();                          // flag seen + w1s ready

    // wave w owns 4 seqs x 16 timesteps: (seq, t) = (gbm*16 + w*4 + g, ch*16 + c)
    const int seqB = gbm * 16 + w * 4;
    const size_t tB = (size_t)ch * 16;

    f16x8 Bs[4][2];
#pragma unroll
    for (int g = 0; g < 4; g++)
#pragma unroll
      for (int kk = 0; kk < 2; kk++)
        Bs[g][kk] = *(const f16x8*)(sx + ((size_t)(seqB + g) * Tdim + tB + c) * Hdim
                                    + kk * 32 + q * 8);

    f32x4 acc2[4][8];
#pragma unroll
    for (int g = 0; g < 4; g++)
#pragma unroll
      for (int nt = 0; nt < 8; nt++) acc2[g][nt] = (f32x4){0.f, 0.f, 0.f, 0.f};

    // ---- prologue: layer1 for kt=0 into rep
    {
#pragma unroll
      for (int ntl = 0; ntl < 2; ntl++) {
        f16x8 A0 = *(const f16x8*)&w1s[ntl * 1024 + lane * 8];
        f16x8 A1 = *(const f16x8*)&w1s[ntl * 1024 + 512 + lane * 8];
        f32x4 bb = *(const f32x4*)(b1 + ntl * 16 + q * 4);
        const int roff = ((2 * ntl + (q >> 1)) * 16 + c) * 8 + (q & 1) * 4;
#pragma unroll
        for (int g = 0; g < 4; g++) {
          f32x4 cc = __builtin_amdgcn_mfma_f32_16x16x32_f16(A0, Bs[g][0], bb, 0, 0, 0);
          cc = __builtin_amdgcn_mfma_f32_16x16x32_f16(A1, Bs[g][1], cc, 0, 0, 0);
          f16x4 pk;
#pragma unroll
          for (int r = 0; r < 4; r++)
            pk[r] = (_Float16)(cc[r] > 0.f ? cc[r] : 0.f);
          *(f16x4*)&rep[w][g][roff] = pk;
        }
      }
    }

#pragma unroll 1
    for (int kt = 0; kt < 16; kt++) {
      const int ktn = kt + 1;
      const bool more = (ktn < 16);
      f16x8 A2[8];                            // layer2 weights for kt (global/L2)
#pragma unroll
      for (int nt = 0; nt < 8; nt++)
        A2[nt] = *(const f16x8*)(w2p + (size_t)kt * 4096 + nt * 512 + lane * 8);
      f16x8 W0[2], W1[2];                     // layer1 weights for kt+1 (LDS)
      f32x4 bb[2];
      {
        const int kts = more ? ktn : kt;      // harmless re-read on last iter
#pragma unroll
        for (int ntl = 0; ntl < 2; ntl++) {
          W0[ntl] = *(const f16x8*)&w1s[kts * 2048 + ntl * 1024 + lane * 8];
          W1[ntl] = *(const f16x8*)&w1s[kts * 2048 + ntl * 1024 + 512 + lane * 8];
          bb[ntl] = *(const f32x4*)(b1 + kts * 32 + ntl * 16 + q * 4);
        }
      }
      f16x8 Ba[4];                            // a1(kt), written last iteration
#pragma unroll
      for (int g = 0; g < 4; g++)
        Ba[g] = *(const f16x8*)&rep[w][g][lane * 8];

      // ---- layer1 for kt+1 -> rep (WAR on Ba covered by the read->write gap)
      if (more) {
#pragma unroll
        for (int ntl = 0; ntl < 2; ntl++) {
          const int roff = ((2 * ntl + (q >> 1)) * 16 + c) * 8 + (q & 1) * 4;
#pragma unroll
          for (int g = 0; g < 4; g++) {
            f32x4 cc = __builtin_amdgcn_mfma_f32_16x16x32_f16(W0[ntl], Bs[g][0], bb[ntl], 0, 0, 0);
            cc = __builtin_amdgcn_mfma_f32_16x16x32_f16(W1[ntl], Bs[g][1], cc, 0, 0, 0);
            f16x4 pk;
#pragma unroll
            for (int r = 0; r < 4; r++)
              pk[r] = (_Float16)(cc[r] > 0.f ? cc[r] : 0.f);
            *(f16x4*)&rep[w][g][roff] = pk;
          }
        }
      }

      // ---- layer2 partial for kt
#pragma unroll
      for (int nt = 0; nt < 8; nt++)
#pragma unroll
        for (int g = 0; g < 4; g++)
          acc2[g][nt] = __builtin_amdgcn_mfma_f32_16x16x32_f16(A2[nt], Ba[g], acc2[g][nt], 0, 0, 0);
    }

    // ---- layer3: out[row] = sum relu(a2 + b2) * w3 + b3
    float part[4] = {0.f, 0.f, 0.f, 0.f};
#pragma unroll
    for (int nt = 0; nt < 8; nt++) {
      f32x4 bb = *(const f32x4*)(b2 + nt * 16 + q * 4);
      f32x4 ww = *(const f32x4*)(w3 + nt * 16 + q * 4);
#pragma unroll
      for (int g = 0; g < 4; g++) {
#pragma unroll
        for (int r = 0; r < 4; r++) {
          float v = acc2[g][nt][r] + bb[r];
          v = v > 0.f ? v : 0.f;
          part[g] = fmaf(v, ww[r], part[g]);
        }
      }
    }
#pragma unroll
    for (int g = 0; g < 4; g++) {
      part[g] += __shfl_xor(part[g], 16, 64);
      part[g] += __shfl_xor(part[g], 32, 64);
    }
    // lane (c,q): row = (seq seqB+q, timestep tB+c); out flat = [seq][t]
    float pv = (q == 0) ? part[0] : (q == 1) ? part[1] : (q == 2) ? part[2] : part[3];
    out[(size_t)(seqB + q) * Tdim + tB + c] = pv + b3[0];
  }
}

// ----------------------------------------------------------------
extern "C" void kernel_launch(void* const* d_in, const int* in_sizes, int n_in,
                              void* d_out, int out_size, void* d_ws, size_t ws_size,
                              hipStream_t stream) {
  const float* x    = (const float*)d_in[0];
  const float* W_ih = (const float*)d_in[1];
  const float* W_hh = (const float*)d_in[2];
  const float* b_ih = (const float*)d_in[3];
  const float* b_hh = (const float*)d_in[4];
  const float* w1   = (const float*)d_in[5];
  const float* b1   = (const float*)d_in[6];
  const float* w2   = (const float*)d_in[7];
  const float* b2   = (const float*)d_in[8];
  const float* w3   = (const float*)d_in[9];
  const float* b3   = (const float*)d_in[10];
  float* out = (float*)d_out;

  char* ws = (char*)d_ws;
  _Float16* sxf = (_Float16*)ws;                               // 52,428,800 B
  _Float16* Wf  = (_Float16*)(ws + 52428800);                  // 36,864 B
  _Float16* w1p = (_Float16*)(ws + 52428800 + 36864);          // 65,536 B
  _Float16* w2p = (_Float16*)(ws + 52428800 + 36864 + 65536);  // 131,072 B
  unsigned int* syncb = (unsigned int*)(ws + 52428800 + 36864 + 65536 + 131072); // 6,404 B
  unsigned int* flags  = syncb;         // [1600]
  unsigned int* ticket = syncb + NMLP;  // [1]

  hipLaunchKernelGGL(prep_kernel, dim3(456), dim3(256), 0, stream,
                     W_ih, W_hh, w1, w2, Wf, w1p, w2p, syncb);
  hipLaunchKernelGGL(fused_kernel, dim3(NGRU + NMLP), dim3(256), 0, stream,
                     x, Wf, b_ih, b_hh, sxf, w1p, w2p, b1, b2, w3, b3, out,
                     flags, ticket);
}

// Round 6
// 241.367 us; speedup vs baseline: 1.2121x; 1.2033x over previous
//
#include <hip/hip_runtime.h>
#include <stdint.h>

#define Tdim 128
#define Zdim 100
#define Sdim 6
#define Hdim 64
#define ZB   3200           // Z*B
#define F1   512
#define F2   128
#define Mrows (ZB * Tdim)   // 409600
#define NGRU 200            // gru-role blocks (ZB/16), one 16-seq stream each
#define NMLP 1600           // mlp-role blocks (NGRU * 8 chunks)

typedef _Float16 f16x8 __attribute__((ext_vector_type(8)));
typedef _Float16 f16x4 __attribute__((ext_vector_type(4)));
typedef float f32x4 __attribute__((ext_vector_type(4)));
typedef uint32_t u32x4 __attribute__((ext_vector_type(4)));

__device__ __forceinline__ float fast_rcp(float x) {
  return __builtin_amdgcn_rcpf(x);   // v_rcp_f32: 1 trans op, no div-fixup chain
}

// ---------------------------------------------------------------- prep
// Wf[192][96] fp16: [W_hh | W_ih | 0] per gate (K=96 fused), for the GRU.
// w1p frag-linear: [kt][ntl][kfrag][lane][8].  32768 f16.
// w2p frag-linear: [kt][nt][lane][8].          65536 f16.
// Also zeroes the producer-consumer sync area (1600 flags + 1 ticket).
__global__ __launch_bounds__(256) void prep_kernel(
    const float* __restrict__ W_ih, const float* __restrict__ W_hh,
    const float* __restrict__ w1, const float* __restrict__ w2,
    _Float16* __restrict__ Wf, _Float16* __restrict__ w1p,
    _Float16* __restrict__ w2p, unsigned int* __restrict__ sync) {
  int i = blockIdx.x * 256 + threadIdx.x;     // grid covers 116736
  if (i < NMLP + 1) sync[i] = 0u;             // flags[1600] + ticket
  if (i < 192 * 96) {
    int g = i / 96, k = i - g * 96;
    float v = (k < 64) ? W_hh[g * 64 + k] : ((k < 70) ? W_ih[g * 6 + (k - 64)] : 0.f);
    Wf[i] = (_Float16)v;
  }
  int j = i - 192 * 96;
  if (j >= 0 && j < 32768) {
    int kt = j >> 11, ntl = (j >> 10) & 1, kf = (j >> 9) & 1;
    int lane = (j >> 3) & 63, e = j & 7;
    int q = lane >> 4, c = lane & 15;
    int row = kt * 32 + ntl * 16 + c;
    int h = kf * 32 + q * 8 + e;
    w1p[j] = (_Float16)w1[row * 64 + h];
  }
  int l = j - 32768;
  if (l >= 0 && l < 65536) {
    int kt = l >> 12, nt = (l >> 9) & 7;
    int lane = (l >> 3) & 63, e = l & 7;
    int q = lane >> 4, c = lane & 15;
    int row = nt * 16 + c;
    int k = kt * 32 + q * 8 + e;
    w2p[l] = (_Float16)w2[row * 512 + k];
  }
}

// ---------------------------------------------------------------- fused GRU+MLP v3
// 1800 blocks x 256 threads. LDS = union EXACTLY 81,920 B (ticket word is
// carved INTO the union: R5's separate __shared__ int pushed the block to
// 82,432 via 512-B rounding -> 1 blk/CU and the overlap design collapsed).
// 2 x 81,920 = 163,840 = exactly 160 KiB -> 2 blocks/CU.
// Role by atomic ticket: first NGRU started blocks take GRU (resident by
// definition -> deadlock-free). GRU = proven 4-wave gate-split step, one
// 16-seq stream per block. MLP = proven 256-thr consumer, one (gru-block,
// chunk) item of 16 seqs x 16 timesteps; co-resident consumers soak the
// GRU's ~60% idle issue slots.
__global__ __launch_bounds__(256, 2) void fused_kernel(
    const float* __restrict__ x, const _Float16* __restrict__ Wf,
    const float* __restrict__ b_ih, const float* __restrict__ b_hh,
    _Float16* __restrict__ sx, const _Float16* __restrict__ w1p,
    const _Float16* __restrict__ w2p, const float* __restrict__ b1,
    const float* __restrict__ b2, const float* __restrict__ w3,
    const float* __restrict__ b3, float* __restrict__ out,
    unsigned int* __restrict__ flags, unsigned int* __restrict__ ticket) {
  union SmemU {
    unsigned int tk;                          // offset 0; dead after role pick
    struct { _Float16 hist[16][16][72]; _Float16 xs[Tdim][16][8]; } g;  // 69,632 B
    struct { _Float16 w1s[32768]; _Float16 rep[4][4][512]; } m;         // 81,920 B
  };
  __shared__ __align__(16) SmemU smem;        // EXACTLY 81,920 B
  const int tid = threadIdx.x;
  if (tid == 0) smem.tk = atomicAdd(ticket, 1u);
  __syncthreads();                            // tk written
  const int tk = (int)smem.tk;
  __syncthreads();                            // all read tk before union reuse

  const int lane = tid & 63;
  const int w = tid >> 6;                     // wave id 0..3
  const int c = lane & 15;                    // MFMA col
  const int q = lane >> 4;                    // quad

  if (tk < NGRU) {
    // =============================== GRU role ===========================
    const int gb = tk;                        // seqs gb*16 .. gb*16+15
    auto& hist = smem.g.hist;
    auto& xs = smem.g.xs;

    // ---- preload x for this block's 16 rows, pre-converted to fp16
    for (int i = 0; i < 8; i++) {
      int idx = i * 256 + tid;                // 0..2047 = (t, row)
      int t = idx >> 4, row = idx & 15;
      int nr = gb * 16 + row;                 // n = z*32 + b
      const float* p = x + (size_t)(nr & 31) * (Tdim * Zdim * Sdim)
                         + (size_t)t * (Zdim * Sdim) + (size_t)(nr >> 5) * Sdim;
      f16x8 v;
      v[0] = (_Float16)p[0]; v[1] = (_Float16)p[1]; v[2] = (_Float16)p[2];
      v[3] = (_Float16)p[3]; v[4] = (_Float16)p[4]; v[5] = (_Float16)p[5];
      v[6] = (_Float16)0.f;  v[7] = (_Float16)0.f;
      *(f16x8*)&xs[t][row][0] = v;
    }

    const int gr0 = w * 16;                   // r-gate tile base
    const int gz0 = 64 + w * 16;              // z-gate tile base
    const int gn0 = 128 + w * 16;             // n-gate tile base

    // A-frags: A[m=c][k=q*8+j] per 16-gate tile, K=96 fused [h|x|0]
    f16x8 Ar[3], Az[3], Anh[2], Ani;
#pragma unroll
    for (int kf = 0; kf < 3; kf++) {
      Ar[kf] = *(const f16x8*)(Wf + (size_t)(gr0 + c) * 96 + kf * 32 + q * 8);
      Az[kf] = *(const f16x8*)(Wf + (size_t)(gz0 + c) * 96 + kf * 32 + q * 8);
    }
    Anh[0] = *(const f16x8*)(Wf + (size_t)(gn0 + c) * 96 + q * 8);
    Anh[1] = *(const f16x8*)(Wf + (size_t)(gn0 + c) * 96 + 32 + q * 8);
    Ani    = *(const f16x8*)(Wf + (size_t)(gn0 + c) * 96 + 64 + q * 8);

    // biases in D-layout (gate-local m = q*4 + r)
    f32x4 Cr, Cz, Cnh, Cni;
    {
      f32x4 bir = *(const f32x4*)(b_ih + gr0 + q * 4);
      f32x4 bhr = *(const f32x4*)(b_hh + gr0 + q * 4);
      f32x4 biz = *(const f32x4*)(b_ih + gz0 + q * 4);
      f32x4 bhz = *(const f32x4*)(b_hh + gz0 + q * 4);
#pragma unroll
      for (int r = 0; r < 4; r++) { Cr[r] = bir[r] + bhr[r]; Cz[r] = biz[r] + bhz[r]; }
      Cnh = *(const f32x4*)(b_hh + gn0 + q * 4);
      Cni = *(const f32x4*)(b_ih + gn0 + q * 4);
    }

    const uint32_t xmask = (q == 0) ? 0xffffffffu : 0u;

    __syncthreads();                          // xs ready

    f16x8 Bh0 = {0, 0, 0, 0, 0, 0, 0, 0};
    f16x8 Bh1 = {0, 0, 0, 0, 0, 0, 0, 0};
    f32x4 hprev = {0.f, 0.f, 0.f, 0.f};

    f32x4 Dr_s, Dz_s, Dni_s;
    {
      u32x4 xv = *(const u32x4*)&xs[0][c][0];
      xv[0] &= xmask; xv[1] &= xmask; xv[2] &= xmask; xv[3] &= xmask;
      f16x8 Bx = *(f16x8*)&xv;
      Dni_s = __builtin_amdgcn_mfma_f32_16x16x32_f16(Ani, Bx, Cni, 0, 0, 0);
      Dr_s  = __builtin_amdgcn_mfma_f32_16x16x32_f16(Ar[2], Bx, Cr, 0, 0, 0);
      Dz_s  = __builtin_amdgcn_mfma_f32_16x16x32_f16(Az[2], Bx, Cz, 0, 0, 0);
    }

#pragma unroll 1
    for (int tch = 0; tch < 8; tch++) {
#pragma unroll 1
      for (int tc = 0; tc < 16; tc++) {
        const int t = tch * 16 + tc;
        f32x4 Dnh = __builtin_amdgcn_mfma_f32_16x16x32_f16(Anh[0], Bh0, Cnh, 0, 0, 0);
        f32x4 Dr  = __builtin_amdgcn_mfma_f32_16x16x32_f16(Ar[0], Bh0, Dr_s, 0, 0, 0);
        f32x4 Dz  = __builtin_amdgcn_mfma_f32_16x16x32_f16(Az[0], Bh0, Dz_s, 0, 0, 0);
        Dnh = __builtin_amdgcn_mfma_f32_16x16x32_f16(Anh[1], Bh1, Dnh, 0, 0, 0);
        Dr  = __builtin_amdgcn_mfma_f32_16x16x32_f16(Ar[1], Bh1, Dr, 0, 0, 0);
        Dz  = __builtin_amdgcn_mfma_f32_16x16x32_f16(Az[1], Bh1, Dz, 0, 0, 0);

        f16x4 pk;
#pragma unroll
        for (int r = 0; r < 4; r++) {
          float er = __expf(-Dr[r]);
          float rr = fast_rcp(1.f + er);
          float ez = __expf(-Dz[r]);
          float zg = fast_rcp(1.f + ez);
          float na = Dni_s[r] + rr * Dnh[r];
          float en = __expf(2.f * na);
          float nn = 1.f - 2.f * fast_rcp(en + 1.f);
          float hnew = nn + zg * (hprev[r] - nn);
          hprev[r] = hnew;
          pk[r] = (_Float16)hnew;
        }
        *(f16x4*)&hist[tc][c][w * 16 + q * 4] = pk;

        if (t + 1 < Tdim) {
          u32x4 xv = *(const u32x4*)&xs[t + 1][c][0];
          xv[0] &= xmask; xv[1] &= xmask; xv[2] &= xmask; xv[3] &= xmask;
          f16x8 Bx = *(f16x8*)&xv;
          Dni_s = __builtin_amdgcn_mfma_f32_16x16x32_f16(Ani, Bx, Cni, 0, 0, 0);
          Dr_s  = __builtin_amdgcn_mfma_f32_16x16x32_f16(Ar[2], Bx, Cr, 0, 0, 0);
          Dz_s  = __builtin_amdgcn_mfma_f32_16x16x32_f16(Az[2], Bx, Cz, 0, 0, 0);
        }
        __syncthreads();                      // h exchange across the 4 gate waves
        Bh0 = *(const f16x8*)&hist[tc][c][q * 8];
        Bh1 = *(const f16x8*)&hist[tc][c][32 + q * 8];
      }
      // coalesced dump of the 16-step chunk; wave w handles rows 4w..4w+3
      {
        const int t0 = tch * 16;
#pragma unroll
        for (int rr2 = 0; rr2 < 4; rr2++) {
          const int row = w * 4 + rr2;
          const int nrow = gb * 16 + row;
          _Float16* dst = sx + (size_t)nrow * Tdim * Hdim + (size_t)t0 * Hdim;
#pragma unroll
          for (int it = 0; it < 2; it++) {
            int idx = it * 64 + lane;         // 0..127
            int tcc = idx >> 3, hd8 = idx & 7;
            f16x8 vv = *(const f16x8*)&hist[tcc][row][hd8 * 8];
            *(f16x8*)(dst + tcc * 64 + hd8 * 8) = vv;
          }
        }
        __syncthreads();                      // dump drained (vmcnt 0) + hist reusable
        if (tid == 0) {
          __threadfence();                    // agent-scope release of sx
          atomicAdd(&flags[gb * 8 + tch], 1u);// publish chunk
        }
      }
    }
  } else {
    // =============================== MLP role ===========================
    const int mid = tk - NGRU;                // 0..1599
    const int ch  = mid / NGRU;               // chunk 0..7 (early tickets -> early chunks)
    const int gbm = mid % NGRU;               // producer gru block
    auto& w1s = smem.m.w1s;
    auto& rep = smem.m.rep;

    // ---- stage all of w1 into LDS while waiting (64 KB, L2-resident)
    {
      const u32x4* srcw = (const u32x4*)w1p;  // 4096 u32x4
      u32x4* dstw = (u32x4*)w1s;
#pragma unroll
      for (int i = 0; i < 16; i++)
        dstw[i * 256 + tid] = srcw[i * 256 + tid];
    }
    // ---- wait for producer chunk
    if (tid == 0) {
      while (__hip_atomic_load(&flags[gbm * 8 + ch], __ATOMIC_RELAXED,
                               __HIP_MEMORY_SCOPE_AGENT) == 0u)
        __builtin_amdgcn_s_sleep(2);
      (void)__hip_atomic_load(&flags[gbm * 8 + ch], __ATOMIC_ACQUIRE,
                              __HIP_MEMORY_SCOPE_AGENT);  // invalidate caches
    }
    __syncthreads();                          // flag seen + w1s ready

    // wave w owns 4 seqs x 16 timesteps: (seq, t) = (gbm*16 + w*4 + g, ch*16 + c)
    const int seqB = gbm * 16 + w * 4;
    const size_t tB = (size_t)ch * 16;

    f16x8 Bs[4][2];
#pragma unroll
    for (int g = 0; g < 4; g++)
#pragma unroll
      for (int kk = 0; kk < 2; kk++)
        Bs[g][kk] = *(const f16x8*)(sx + ((size_t)(seqB + g) * Tdim + tB + c) * Hdim
                                    + kk * 32 + q * 8);

    f32x4 acc2[4][8];
#pragma unroll
    for (int g = 0; g < 4; g++)
#pragma unroll
      for (int nt = 0; nt < 8; nt++) acc2[g][nt] = (f32x4){0.f, 0.f, 0.f, 0.f};

    // ---- prologue: layer1 for kt=0 into rep
    {
#pragma unroll
      for (int ntl = 0; ntl < 2; ntl++) {
        f16x8 A0 = *(const f16x8*)&w1s[ntl * 1024 + lane * 8];
        f16x8 A1 = *(const f16x8*)&w1s[ntl * 1024 + 512 + lane * 8];
        f32x4 bb = *(const f32x4*)(b1 + ntl * 16 + q * 4);
        const int roff = ((2 * ntl + (q >> 1)) * 16 + c) * 8 + (q & 1) * 4;
#pragma unroll
        for (int g = 0; g < 4; g++) {
          f32x4 cc = __builtin_amdgcn_mfma_f32_16x16x32_f16(A0, Bs[g][0], bb, 0, 0, 0);
          cc = __builtin_amdgcn_mfma_f32_16x16x32_f16(A1, Bs[g][1], cc, 0, 0, 0);
          f16x4 pk;
#pragma unroll
          for (int r = 0; r < 4; r++)
            pk[r] = (_Float16)(cc[r] > 0.f ? cc[r] : 0.f);
          *(f16x4*)&rep[w][g][roff] = pk;
        }
      }
    }

#pragma unroll 1
    for (int kt = 0; kt < 16; kt++) {
      const int ktn = kt + 1;
      const bool more = (ktn < 16);
      f16x8 A2[8];                            // layer2 weights for kt (global/L2)
#pragma unroll
      for (int nt = 0; nt < 8; nt++)
        A2[nt] = *(const f16x8*)(w2p + (size_t)kt * 4096 + nt * 512 + lane * 8);
      f16x8 W0[2], W1[2];                     // layer1 weights for kt+1 (LDS)
      f32x4 bb[2];
      {
        const int kts = more ? ktn : kt;      // harmless re-read on last iter
#pragma unroll
        for (int ntl = 0; ntl < 2; ntl++) {
          W0[ntl] = *(const f16x8*)&w1s[kts * 2048 + ntl * 1024 + lane * 8];
          W1[ntl] = *(const f16x8*)&w1s[kts * 2048 + ntl * 1024 + 512 + lane * 8];
          bb[ntl] = *(const f32x4*)(b1 + kts * 32 + ntl * 16 + q * 4);
        }
      }
      f16x8 Ba[4];                            // a1(kt), written last iteration
#pragma unroll
      for (int g = 0; g < 4; g++)
        Ba[g] = *(const f16x8*)&rep[w][g][lane * 8];

      // ---- layer1 for kt+1 -> rep (WAR on Ba covered by the read->write gap)
      if (more) {
#pragma unroll
        for (int ntl = 0; ntl < 2; ntl++) {
          const int roff = ((2 * ntl + (q >> 1)) * 16 + c) * 8 + (q & 1) * 4;
#pragma unroll
          for (int g = 0; g < 4; g++) {
            f32x4 cc = __builtin_amdgcn_mfma_f32_16x16x32_f16(W0[ntl], Bs[g][0], bb[ntl], 0, 0, 0);
            cc = __builtin_amdgcn_mfma_f32_16x16x32_f16(W1[ntl], Bs[g][1], cc, 0, 0, 0);
            f16x4 pk;
#pragma unroll
            for (int r = 0; r < 4; r++)
              pk[r] = (_Float16)(cc[r] > 0.f ? cc[r] : 0.f);
            *(f16x4*)&rep[w][g][roff] = pk;
          }
        }
      }

      // ---- layer2 partial for kt
#pragma unroll
      for (int nt = 0; nt < 8; nt++)
#pragma unroll
        for (int g = 0; g < 4; g++)
          acc2[g][nt] = __builtin_amdgcn_mfma_f32_16x16x32_f16(A2[nt], Ba[g], acc2[g][nt], 0, 0, 0);
    }

    // ---- layer3: out[row] = sum relu(a2 + b2) * w3 + b3
    float part[4] = {0.f, 0.f, 0.f, 0.f};
#pragma unroll
    for (int nt = 0; nt < 8; nt++) {
      f32x4 bb = *(const f32x4*)(b2 + nt * 16 + q * 4);
      f32x4 ww = *(const f32x4*)(w3 + nt * 16 + q * 4);
#pragma unroll
      for (int g = 0; g < 4; g++) {
#pragma unroll
        for (int r = 0; r < 4; r++) {
          float v = acc2[g][nt][r] + bb[r];
          v = v > 0.f ? v : 0.f;
          part[g] = fmaf(v, ww[r], part[g]);
        }
      }
    }
#pragma unroll
    for (int g = 0; g < 4; g++) {
      part[g] += __shfl_xor(part[g], 16, 64);
      part[g] += __shfl_xor(part[g], 32, 64);
    }
    // lane (c,q): row = (seq seqB+q, timestep tB+c); out flat = [seq][t]
    float pv = (q == 0) ? part[0] : (q == 1) ? part[1] : (q == 2) ? part[2] : part[3];
    out[(size_t)(seqB + q) * Tdim + tB + c] = pv + b3[0];
  }
}

// ----------------------------------------------------------------
extern "C" void kernel_launch(void* const* d_in, const int* in_sizes, int n_in,
                              void* d_out, int out_size, void* d_ws, size_t ws_size,
                              hipStream_t stream) {
  const float* x    = (const float*)d_in[0];
  const float* W_ih = (const float*)d_in[1];
  const float* W_hh = (const float*)d_in[2];
  const float* b_ih = (const float*)d_in[3];
  const float* b_hh = (const float*)d_in[4];
  const float* w1   = (const float*)d_in[5];
  const float* b1   = (const float*)d_in[6];
  const float* w2   = (const float*)d_in[7];
  const float* b2   = (const float*)d_in[8];
  const float* w3   = (const float*)d_in[9];
  const float* b3   = (const float*)d_in[10];
  float* out = (float*)d_out;

  char* ws = (char*)d_ws;
  _Float16* sxf = (_Float16*)ws;                               // 52,428,800 B
  _Float16* Wf  = (_Float16*)(ws + 52428800);                  // 36,864 B
  _Float16* w1p = (_Float16*)(ws + 52428800 + 36864);          // 65,536 B
  _Float16* w2p = (_Float16*)(ws + 52428800 + 36864 + 65536);  // 131,072 B
  unsigned int* syncb = (unsigned int*)(ws + 52428800 + 36864 + 65536 + 131072); // 6,404 B
  unsigned int* flags  = syncb;         // [1600]
  unsigned int* ticket = syncb + NMLP;  // [1]

  hipLaunchKernelGGL(prep_kernel, dim3(456), dim3(256), 0, stream,
                     W_ih, W_hh, w1, w2, Wf, w1p, w2p, syncb);
  hipLaunchKernelGGL(fused_kernel, dim3(NGRU + NMLP), dim3(256), 0, stream,
                     x, Wf, b_ih, b_hh, sxf, w1p, w2p, b1, b2, w3, b3, out,
                     flags, ticket);
}